// Round 2
// baseline (641.098 us; speedup 1.0000x reference)
//
#include <hip/hip_runtime.h>
#include <math.h>

#define H_IN 512
#define W_IN 512
#define N_ANGLES 180
#define PAD 106
#define P 724
#define RBLK 181          // row-blocks per angle (4 rows each)

// Pre-kernel: 180 (cos,sin) pairs into workspace.
__global__ void sincos_kernel(float2* __restrict__ sc) {
    int a = threadIdx.x;
    if (a < N_ANGLES) {
        float deg = (float)a * (180.0f / 179.0f);
        float ang = deg * (float)(M_PI / 180.0);
        sc[a] = make_float2(cosf(ang), sinf(ang));
    }
}

// Wave-per-row: block = (angle, 4 consecutive rows). 64 lanes stride columns.
__global__ __launch_bounds__(256) void radon_kernel(
    const float* __restrict__ x,      // [512,512]
    const float2* __restrict__ sc,    // [180] (cos,sin)
    float* __restrict__ sino,         // [180,724]
    float* __restrict__ rot)          // [180,724,724]
{
    const int b    = blockIdx.x;
    const int a    = b / RBLK;
    const int rblk = b - a * RBLK;
    const int wid  = threadIdx.x >> 6;
    const int lane = threadIdx.x & 63;
    const int row  = rblk * 4 + wid;

    const float2 cs = sc[a];
    const float c = cs.x, s = cs.y;

    // Xn(j) = j*s1 + s0 ; ix_unpadded = 362*xs + 255.5 (PAD folded in)
    const float s1 = 2.0f / 724.0f;
    const float s0 = 1.0f / 724.0f - 1.0f;
    const float g  = 362.0f * s1;

    const float Yn  = (2.0f * (float)row + 1.0f) * (1.0f / 724.0f) - 1.0f;
    const float sYn = s * Yn;
    const float cYn = c * Yn;

    // ix(j) = jf*dix + bix ; iy(j) = jf*diy + biy   (unpadded pixel coords)
    const float dix = c * g;
    const float diy = s * g;
    const float bix = fmaf(362.0f, fmaf(c, s0, -sYn), 255.5f);
    const float biy = fmaf(362.0f, fmaf(s, s0,  cYn), 255.5f);

    float* __restrict__ rrow = rot + (size_t)(a * P + row) * P;

    float lsum = 0.0f;
    float jf = (float)lane;
    int   j  = lane;

    #pragma unroll
    for (int it = 0; it < 12; ++it) {
        // 724 = 11*64 + 20: last iteration only lanes < 20
        if (it < 11 || lane < 20) {
            float ix = fmaf(jf, dix, bix);
            float iy = fmaf(jf, diy, biy);
            float fx = floorf(ix);
            float fy = floorf(iy);
            float wx = ix - fx;
            float wy = iy - fy;
            int x0 = (int)fx;
            int y0 = (int)fy;
            int x1 = x0 + 1;
            int y1 = y0 + 1;

            // clamped addresses (always safe), masks as selects
            int xc0 = min(max(x0, 0), W_IN - 1);
            int xc1 = min(max(x1, 0), W_IN - 1);
            int yc0 = min(max(y0, 0), H_IN - 1);
            int yc1 = min(max(y1, 0), H_IN - 1);
            int r0 = yc0 << 9;
            int r1 = yc1 << 9;

            float v00 = x[r0 + xc0];
            float v01 = x[r0 + xc1];
            float v10 = x[r1 + xc0];
            float v11 = x[r1 + xc1];

            bool mx0 = (unsigned)x0 < (unsigned)W_IN;
            bool mx1 = (unsigned)x1 < (unsigned)W_IN;
            bool my0 = (unsigned)y0 < (unsigned)H_IN;
            bool my1 = (unsigned)y1 < (unsigned)H_IN;
            v00 = (mx0 && my0) ? v00 : 0.0f;
            v01 = (mx1 && my0) ? v01 : 0.0f;
            v10 = (mx0 && my1) ? v10 : 0.0f;
            v11 = (mx1 && my1) ? v11 : 0.0f;

            // 2-level lerp (6 VALU)
            float a0  = fmaf(v01 - v00, wx, v00);
            float a1  = fmaf(v11 - v10, wx, v10);
            float val = fmaf(a1 - a0, wy, a0);

            __builtin_nontemporal_store(val, &rrow[j]);
            lsum += val;
        }
        jf += 64.0f;
        j  += 64;
    }

    // wave-wide row sum (each row owned by exactly one wave)
    #pragma unroll
    for (int off = 32; off > 0; off >>= 1)
        lsum += __shfl_down(lsum, off, 64);
    if (lane == 0)
        sino[a * P + row] = lsum;
}

extern "C" void kernel_launch(void* const* d_in, const int* in_sizes, int n_in,
                              void* d_out, int out_size, void* d_ws, size_t ws_size,
                              hipStream_t stream) {
    const float* x = (const float*)d_in[0];
    float* sino = (float*)d_out;                   // [180*724]
    float* rot  = sino + (size_t)N_ANGLES * P;     // [180*724*724]
    float2* sc  = (float2*)d_ws;                   // 180*8 = 1440 B scratch

    sincos_kernel<<<dim3(1), dim3(192), 0, stream>>>(sc);
    radon_kernel<<<dim3(N_ANGLES * RBLK), dim3(256), 0, stream>>>(x, sc, sino, rot);
}